// Round 2
// baseline (517.411 us; speedup 1.0000x reference)
//
#include <hip/hip_runtime.h>

typedef __attribute__((ext_vector_type(8))) short s16x8;
typedef __attribute__((ext_vector_type(4))) short s16x4;
typedef __attribute__((ext_vector_type(4))) float f32x4;

#define MFMA16(a,b,c) __builtin_amdgcn_mfma_f32_16x16x32_bf16((a),(b),(c),0,0,0)

__device__ __forceinline__ unsigned short f2bf(float f) {
    unsigned u = __builtin_bit_cast(unsigned, f);
    u = (u + 0x7FFFu + ((u >> 16) & 1u)) >> 16;
    return (unsigned short)u;
}

// ---------------- ws layout (bytes), ~77.3 MB total ----------------
#define MB ((size_t)1 << 20)
#define WT_OFF   ((size_t)0)        // Wt[384][1024] bf16 = 768 KB (row = mat*128+h)
#define QKV_OFF  (1*MB)             // QKV[3][32768][128] bf16 = 24 MB
#define VT0_OFF  (25*MB)            // per-config V gathered+transposed: [seg][128 h][1024 key]
#define VT1_OFF  (33*MB)
#define VT2_OFF  (37*MB)
#define VT3_OFF  (39*MB)
#define KG1_OFF  (40*MB)            // per-config K gathered (contig): [seg][1024 key][128 h]; c0 reads K directly
#define KG2_OFF  (44*MB)
#define KG3_OFF  (46*MB)
#define O0_OFF   (47*MB)            // per-config unnormalized O fp32 [seg*1024][128]
#define O1_OFF   (63*MB)
#define O2_OFF   (71*MB)
#define O3_OFF   (75*MB)
#define L0_OFF   (77*MB)            // per-config denominators fp32
#define L1_OFF   (L0_OFF + (size_t)131072)
#define L2_OFF   (L1_OFF + (size_t)65536)
#define L3_OFF   (L2_OFF + (size_t)32768)

// ---------------- W transpose: Wt[mat*128+h][c] = bf16(W[c][h]) ----------------
__global__ __launch_bounds__(256) void k_wt(const float* __restrict__ Wq, const float* __restrict__ Wk,
                                            const float* __restrict__ Wv, unsigned short* __restrict__ Wt) {
    int id = blockIdx.x * 256 + threadIdx.x;   // 0..393215
    int mat = id >> 17;
    int rem = id & 131071;
    int h = rem >> 10, c = rem & 1023;
    const float* W = (mat == 0) ? Wq : (mat == 1) ? Wk : Wv;
    Wt[id] = f2bf(W[c * 128 + h]);
}

// ---------------- fused QKV GEMM: [32768 x 1024] @ [1024 x 384], x read from HBM exactly once ----
// 512 threads = 8 waves as 2x4: wave = 32 rows x 96 cols. grid 512 (64-row m-tiles) = 2 blocks/CU.
__global__ __launch_bounds__(512, 4) void k_qkv(const float* __restrict__ x, const unsigned short* __restrict__ Wt,
                                                unsigned short* __restrict__ QKV) {
    __shared__ unsigned short As[64][72];    // A[row][k], +8 pad
    __shared__ unsigned short Cs[32][392];   // epilogue staging (one 32-row half at a time)
    const int mt  = blockIdx.x;
    const int tid = threadIdx.x;
    const int lane = tid & 63, wv = tid >> 6;
    const int quad = lane >> 4, m16 = lane & 15;
    const int wr = wv >> 2, wc = wv & 3;     // wave owns rows wr*32.. cols wc*96..

    f32x4 acc[2][6];
#pragma unroll
    for (int i = 0; i < 2; i++)
#pragma unroll
        for (int j = 0; j < 6; j++) acc[i][j] = (f32x4)0.f;

    const float* xb = x + (size_t)mt * 64 * 1024;
    const int r0 = tid >> 4, kl = (tid & 15) * 4;   // thread's two staging slots: rows r0, r0+32

    // software pipeline: prefetch chunk kk into registers while MFMAing chunk kk-64
    float4 pf0 = *(const float4*)(xb + (size_t)r0 * 1024 + kl);
    float4 pf1 = *(const float4*)(xb + (size_t)(r0 + 32) * 1024 + kl);

    for (int kk = 0; kk < 1024; kk += 64) {
        s16x4 c0, c1;
        c0[0] = (short)f2bf(pf0.x); c0[1] = (short)f2bf(pf0.y);
        c0[2] = (short)f2bf(pf0.z); c0[3] = (short)f2bf(pf0.w);
        c1[0] = (short)f2bf(pf1.x); c1[1] = (short)f2bf(pf1.y);
        c1[2] = (short)f2bf(pf1.z); c1[3] = (short)f2bf(pf1.w);
        *(s16x4*)&As[r0][kl]      = c0;
        *(s16x4*)&As[r0 + 32][kl] = c1;
        if (kk < 960) {   // issue next chunk's loads; they fly across the MFMA section
            pf0 = *(const float4*)(xb + (size_t)r0 * 1024 + kk + 64 + kl);
            pf1 = *(const float4*)(xb + (size_t)(r0 + 32) * 1024 + kk + 64 + kl);
        }
        __syncthreads();
#pragma unroll
        for (int c32 = 0; c32 < 2; c32++) {
            s16x8 a[2], b[6];
#pragma unroll
            for (int rt = 0; rt < 2; rt++)
                a[rt] = *(const s16x8*)&As[wr * 32 + rt * 16 + m16][c32 * 32 + quad * 8];
#pragma unroll
            for (int ct = 0; ct < 6; ct++)   // Wt direct from global: 768 KB, L2-resident
                b[ct] = *(const s16x8*)(Wt + (size_t)(wc * 96 + ct * 16 + m16) * 1024 + kk + c32 * 32 + quad * 8);
#pragma unroll
            for (int rt = 0; rt < 2; rt++)
#pragma unroll
                for (int ct = 0; ct < 6; ct++) acc[rt][ct] = MFMA16(a[rt], b[ct], acc[rt][ct]);
        }
        __syncthreads();
    }

    // epilogue: two 32-row passes through LDS -> coalesced 16B stores
#pragma unroll
    for (int p = 0; p < 2; p++) {
        if (wr == p) {
#pragma unroll
            for (int rt = 0; rt < 2; rt++)
#pragma unroll
                for (int ct = 0; ct < 6; ct++)
#pragma unroll
                    for (int rg = 0; rg < 4; rg++)
                        Cs[rt * 16 + quad * 4 + rg][wc * 96 + ct * 16 + m16] = f2bf(acc[rt][ct][rg]);
        }
        __syncthreads();
#pragma unroll
        for (int i = 0; i < 3; i++) {
            int id = tid + 512 * i;              // 0..1535 -> 32 rows x 48 col-chunks
            int row = id / 48, cc = id % 48;
            int col = cc * 8, mat = col >> 7, h = col & 127;
            s16x8 v = *(const s16x8*)&Cs[row][col];
            *(s16x8*)(QKV + (size_t)mat * 4194304 + ((size_t)(mt * 64 + p * 32 + row)) * 128 + h) = v;
        }
        __syncthreads();
    }
}

// ---------------- Vt decode: 480 blocks of (cfg, b, s, tile8) ----------------
__device__ __forceinline__ void decode_vt(int bid, int& c, int& b, int& s, int& t8) {
    int base;
    if (bid < 256)      { c = 0; base = 0; }
    else if (bid < 384) { c = 1; base = 256; }
    else if (bid < 448) { c = 2; base = 384; }
    else                { c = 3; base = 448; }
    int rem = bid - base;
    int sh = 6 - c;
    b = rem >> sh;
    int rr = rem & ((1 << sh) - 1);
    s = rr >> 3; t8 = rr & 7;
}

// ---------------- gather pass: Vt (transposed) for all cfgs + Kg (contig) for cfgs 1..3 ----------------
__global__ __launch_bounds__(256) void k_gather(const unsigned short* __restrict__ QKV, char* __restrict__ ws) {
    const unsigned short* K = QKV + (size_t)1 * 4194304;
    const unsigned short* V = QKV + (size_t)2 * 4194304;
    int bid = blockIdx.x, tid = threadIdx.x;
    if (bid < 480) {   // ---- Vt: gather + 8x8 register transpose ----
        int c, b, s, kb; decode_vt(bid, c, b, s, kb);
        const int S = 8 >> c, r = 1 << c, wseg = 1024 << c;
        const size_t vtoff[4] = {VT0_OFF, VT1_OFF, VT2_OFF, VT3_OFF};
        unsigned short* Vt = (unsigned short*)(ws + vtoff[c]) + ((size_t)(b * S + s)) * 128 * 1024;
        int kq8 = tid & 15, hq = tid >> 4;
        int key0 = kb * 128 + kq8 * 8;
        s16x8 in[8];
#pragma unroll
        for (int i = 0; i < 8; i++) {
            int tok = s * wseg + (key0 + i) * r;
            in[i] = *(const s16x8*)(V + ((size_t)(b * 8192 + tok)) * 128 + hq * 8);
        }
#pragma unroll
        for (int jh = 0; jh < 8; jh++) {
            s16x8 o;
#pragma unroll
            for (int i = 0; i < 8; i++) o[i] = in[i][jh];
            *(s16x8*)(Vt + (size_t)(hq * 8 + jh) * 1024 + key0) = o;
        }
    } else {           // ---- Kg: row gather for c = 1..3 ----
        int r2 = bid - 480, c;
        if (r2 < 128)      { c = 1; }
        else if (r2 < 192) { c = 2; r2 -= 128; }
        else               { c = 3; r2 -= 192; }
        const int S = 8 >> c, r = 1 << c, wseg = 1024 << c;
        int b = r2 >> (6 - c);
        int rem = r2 & ((1 << (6 - c)) - 1);
        int s = rem >> 3, kb = rem & 7;
        const size_t kgoff[4] = {0, KG1_OFF, KG2_OFF, KG3_OFF};
        unsigned short* Kg = (unsigned short*)(ws + kgoff[c]) + ((size_t)(b * S + s)) * 128 * 1024;
        int row = tid >> 1, hh = (tid & 1) * 64;
        const unsigned short* src = K + ((size_t)(b * 8192 + s * wseg + (kb * 128 + row) * r)) * 128 + hh;
        unsigned short* dst = Kg + ((size_t)(kb * 128 + row)) * 128 + hh;
#pragma unroll
        for (int i = 0; i < 8; i++)
            *(s16x8*)(dst + i * 8) = *(const s16x8*)(src + i * 8);
    }
}

// ---------------- attn decode: 960 blocks of (cfg, b, s, qt16) ----------------
__device__ __forceinline__ void decode_attn(int bid, int& c, int& b, int& s, int& qt) {
    int rem;
    if (bid < 512)      { c = 0; rem = bid; }
    else if (bid < 768) { c = 1; rem = bid - 512; }
    else if (bid < 896) { c = 2; rem = bid - 768; }
    else                { c = 3; rem = bid - 896; }
    qt = rem & 15;
    int r2 = rem >> 4;
    int S = 8 >> c;
    s = r2 & (S - 1);
    b = r2 >> (3 - c);
}

// ---------------- per-segment causal attention, unnormalized; 64-row q-tiles, zero barriers ----------------
__global__ __launch_bounds__(256, 3) void k_attn(const unsigned short* __restrict__ QKV,
                                                 char* __restrict__ ws) {
    __shared__ unsigned short Ps[64][72];    // P round-trip; rows wave-private
    int c, b, s, qt; decode_attn(blockIdx.x, c, b, s, qt);
    const int S = 8 >> c, r = 1 << c, wseg = 1024 << c;
    const size_t vtoff[4] = {VT0_OFF, VT1_OFF, VT2_OFF, VT3_OFF};
    const size_t ooff[4]  = {O0_OFF, O1_OFF, O2_OFF, O3_OFF};
    const size_t loff[4]  = {L0_OFF, L1_OFF, L2_OFF, L3_OFF};
    const size_t kgoff[4] = {0, KG1_OFF, KG2_OFF, KG3_OFF};
    const unsigned short* Q  = QKV;
    const unsigned short* Kfull = QKV + (size_t)1 * 4194304;
    const unsigned short* Vt = (const unsigned short*)(ws + vtoff[c]) + ((size_t)(b * S + s)) * 128 * 1024;
    // contiguous per-segment K: c==0 is already contiguous in K itself
    const unsigned short* Kg = (c == 0)
        ? Kfull + ((size_t)(b * 8192 + s * 1024)) * 128
        : (const unsigned short*)(ws + kgoff[c]) + ((size_t)(b * S + s)) * 128 * 1024;
    float* Oc = (float*)(ws + ooff[c]) + ((size_t)((b * S + s) * 1024 + qt * 64)) * 128;
    float* Lc = (float*)(ws + loff[c]) + (size_t)(b * S + s) * 1024 + qt * 64;

    const int tid = threadIdx.x, lane = tid & 63, wv = tid >> 6;
    const int quad = lane >> 4, m16 = lane & 15;
    const float SCE = 0.08838834764831845f;   // 1/sqrt(128)

    // Q fragments resident (wave owns 16 q-rows: qt*64 + wv*16 ..)
    const int qrow = qt * 64 + wv * 16;
    s16x8 qf[4];
    {
        int tok = s * wseg + (qrow + m16) * r;
        const unsigned short* qp = Q + ((size_t)(b * 8192 + tok)) * 128;
#pragma unroll
        for (int c4 = 0; c4 < 4; c4++) qf[c4] = *(const s16x8*)(qp + c4 * 32 + quad * 8);
    }
    f32x4 oacc[8];
#pragma unroll
    for (int i = 0; i < 8; i++) oacc[i] = (f32x4)0.f;
    float lsum[4] = {};

    for (int j = 0; j <= qt; j++) {
        // S = Q K^T over a 16x64 tile (keys j*64..j*64+63)
        f32x4 sa[4];
#pragma unroll
        for (int t = 0; t < 4; t++) sa[t] = (f32x4)0.f;
#pragma unroll
        for (int ct = 0; ct < 4; ct++) {
            const unsigned short* kp = Kg + ((size_t)(j * 64 + ct * 16 + m16)) * 128;
#pragma unroll
            for (int c4 = 0; c4 < 4; c4++) {
                s16x8 kf = *(const s16x8*)(kp + c4 * 32 + quad * 8);
                sa[ct] = MFMA16(qf[c4], kf, sa[ct]);
            }
        }
        // exp + diagonal causal mask; write P to wave-private LDS rows
        const bool diag = (j == qt);
        const int rowL = wv * 16 + quad * 4;   // + rg
#pragma unroll
        for (int ct = 0; ct < 4; ct++) {
            int colL = ct * 16 + m16;
#pragma unroll
            for (int rg = 0; rg < 4; rg++) {
                float p = __expf(sa[ct][rg] * SCE);
                if (diag && colL > (wv * 16 + quad * 4 + rg)) p = 0.f;
                lsum[rg] += p;
                Ps[rowL + rg][colL] = f2bf(p);
            }
        }
        // O += P V  (A from LDS, B direct 16B from pre-transposed Vt)
#pragma unroll
        for (int kc = 0; kc < 2; kc++) {
            s16x8 a = *(const s16x8*)&Ps[wv * 16 + m16][kc * 32 + quad * 8];
#pragma unroll
            for (int nt = 0; nt < 8; nt++) {
                s16x8 bv = *(const s16x8*)(Vt + (size_t)(nt * 16 + m16) * 1024 + j * 64 + kc * 32 + quad * 8);
                oacc[nt] = MFMA16(a, bv, oacc[nt]);
            }
        }
    }
    // reduce denominators across the 16 lanes of each row
#pragma unroll
    for (int rg = 0; rg < 4; rg++) {
        float v = lsum[rg];
        v += __shfl_xor(v, 1); v += __shfl_xor(v, 2);
        v += __shfl_xor(v, 4); v += __shfl_xor(v, 8);
        lsum[rg] = v;
    }
#pragma unroll
    for (int nt = 0; nt < 8; nt++)
#pragma unroll
        for (int rg = 0; rg < 4; rg++)
            Oc[(size_t)(wv * 16 + quad * 4 + rg) * 128 + nt * 16 + m16] = oacc[nt][rg];
    if (m16 == 0) {
#pragma unroll
        for (int rg = 0; rg < 4; rg++)
            Lc[wv * 16 + quad * 4 + rg] = lsum[rg];
    }
}

// ---------------- cross-config combine: out = sum_c O_c / sum_c L_c ----------------
__global__ __launch_bounds__(256) void k_combine(const char* __restrict__ ws, float* __restrict__ out) {
    int gid = blockIdx.x * 256 + threadIdx.x;   // 1048576 threads
    int rown = gid >> 5;                        // b*8192 + n
    int h4 = (gid & 31) * 4;
    int b = rown >> 13, n = rown & 8191;
    const size_t ooff[4] = {O0_OFF, O1_OFF, O2_OFF, O3_OFF};
    const size_t loff[4] = {L0_OFF, L1_OFF, L2_OFF, L3_OFF};
    float denom = 0.f;
    float4 acc = {0.f, 0.f, 0.f, 0.f};
#pragma unroll
    for (int c = 0; c < 4; c++) {
        if ((n & ((1 << c) - 1)) == 0) {        // config c covers n iff n % 2^c == 0
            int s = n >> (10 + c);
            int i = (n & ((1024 << c) - 1)) >> c;
            int rowc = b * (8192 >> c) + (s << 10) + i;
            denom += *((const float*)(ws + loff[c]) + rowc);
            const float4 o = *(const float4*)((const float*)(ws + ooff[c]) + (size_t)rowc * 128 + h4);
            acc.x += o.x; acc.y += o.y; acc.z += o.z; acc.w += o.w;
        }
    }
    float inv = 1.f / denom;
    float4 res = {acc.x * inv, acc.y * inv, acc.z * inv, acc.w * inv};
    *(float4*)(out + (size_t)rown * 128 + h4) = res;
}

extern "C" void kernel_launch(void* const* d_in, const int* in_sizes, int n_in,
                              void* d_out, int out_size, void* d_ws, size_t ws_size,
                              hipStream_t stream) {
    const float* x  = (const float*)d_in[0];
    const float* Wq = (const float*)d_in[1];
    const float* Wk = (const float*)d_in[2];
    const float* Wv = (const float*)d_in[3];
    char* ws = (char*)d_ws;
    unsigned short* Wt  = (unsigned short*)(ws + WT_OFF);
    unsigned short* QKV = (unsigned short*)(ws + QKV_OFF);

    k_wt<<<1536, 256, 0, stream>>>(Wq, Wk, Wv, Wt);
    k_qkv<<<512, 512, 0, stream>>>(x, Wt, QKV);
    k_gather<<<704, 256, 0, stream>>>(QKV, ws);
    k_attn<<<960, 256, 0, stream>>>(QKV, ws);
    k_combine<<<4096, 256, 0, stream>>>(ws, (float*)d_out);
}

// Round 3
// 348.552 us; speedup vs baseline: 1.4845x; 1.4845x over previous
//
#include <hip/hip_runtime.h>

typedef __attribute__((ext_vector_type(8))) short s16x8;
typedef __attribute__((ext_vector_type(4))) short s16x4;
typedef __attribute__((ext_vector_type(4))) float f32x4;

#define MFMA16(a,b,c) __builtin_amdgcn_mfma_f32_16x16x32_bf16((a),(b),(c),0,0,0)

// async global->LDS, 16B per lane; LDS dest is wave-uniform base + lane*16
#define GLOAD_LDS16(g, l) \
    __builtin_amdgcn_global_load_lds((const __attribute__((address_space(1))) void*)(g), \
                                     (__attribute__((address_space(3))) void*)(l), 16, 0, 0)

__device__ __forceinline__ unsigned short f2bf(float f) {
    unsigned u = __builtin_bit_cast(unsigned, f);
    u = (u + 0x7FFFu + ((u >> 16) & 1u)) >> 16;
    return (unsigned short)u;
}

// ---------------- ws layout (bytes), ~77.3 MB total ----------------
#define MB ((size_t)1 << 20)
#define WT_OFF   ((size_t)0)        // Wt[384][1024] bf16 (row = mat*128+h)
#define QKV_OFF  (1*MB)             // QKV[3][32768][128] bf16 = 24 MB
#define VT0_OFF  (25*MB)            // per-config V, TILED: [seg][16 jt][128 h][64 key] bf16
#define VT1_OFF  (33*MB)
#define VT2_OFF  (37*MB)
#define VT3_OFF  (39*MB)
#define KG1_OFF  (40*MB)            // per-config K gathered contig: [seg][1024 key][128 h]; c0 reads K directly
#define KG2_OFF  (44*MB)
#define KG3_OFF  (46*MB)
#define O0_OFF   (47*MB)            // per-config unnormalized O fp32 [seg*1024][128]
#define O1_OFF   (63*MB)
#define O2_OFF   (71*MB)
#define O3_OFF   (75*MB)
#define L0_OFF   (77*MB)            // per-config denominators fp32
#define L1_OFF   (L0_OFF + (size_t)131072)
#define L2_OFF   (L1_OFF + (size_t)65536)
#define L3_OFF   (L2_OFF + (size_t)32768)

// ---------------- W transpose: Wt[mat*128+h][c] = bf16(W[c][h]) ----------------
__global__ __launch_bounds__(256) void k_wt(const float* __restrict__ Wq, const float* __restrict__ Wk,
                                            const float* __restrict__ Wv, unsigned short* __restrict__ Wt) {
    int id = blockIdx.x * 256 + threadIdx.x;
    int mat = id >> 17;
    int rem = id & 131071;
    int h = rem >> 10, c = rem & 1023;
    const float* W = (mat == 0) ? Wq : (mat == 1) ? Wk : Wv;
    Wt[id] = f2bf(W[c * 128 + h]);
}

// ---------------- fused QKV GEMM (unchanged from R2) ----------------
__global__ __launch_bounds__(512, 4) void k_qkv(const float* __restrict__ x, const unsigned short* __restrict__ Wt,
                                                unsigned short* __restrict__ QKV) {
    __shared__ unsigned short As[64][72];
    __shared__ unsigned short Cs[32][392];
    const int mt  = blockIdx.x;
    const int tid = threadIdx.x;
    const int lane = tid & 63, wv = tid >> 6;
    const int quad = lane >> 4, m16 = lane & 15;
    const int wr = wv >> 2, wc = wv & 3;

    f32x4 acc[2][6];
#pragma unroll
    for (int i = 0; i < 2; i++)
#pragma unroll
        for (int j = 0; j < 6; j++) acc[i][j] = (f32x4)0.f;

    const float* xb = x + (size_t)mt * 64 * 1024;
    const int r0 = tid >> 4, kl = (tid & 15) * 4;

    float4 pf0 = *(const float4*)(xb + (size_t)r0 * 1024 + kl);
    float4 pf1 = *(const float4*)(xb + (size_t)(r0 + 32) * 1024 + kl);

    for (int kk = 0; kk < 1024; kk += 64) {
        s16x4 c0, c1;
        c0[0] = (short)f2bf(pf0.x); c0[1] = (short)f2bf(pf0.y);
        c0[2] = (short)f2bf(pf0.z); c0[3] = (short)f2bf(pf0.w);
        c1[0] = (short)f2bf(pf1.x); c1[1] = (short)f2bf(pf1.y);
        c1[2] = (short)f2bf(pf1.z); c1[3] = (short)f2bf(pf1.w);
        *(s16x4*)&As[r0][kl]      = c0;
        *(s16x4*)&As[r0 + 32][kl] = c1;
        if (kk < 960) {
            pf0 = *(const float4*)(xb + (size_t)r0 * 1024 + kk + 64 + kl);
            pf1 = *(const float4*)(xb + (size_t)(r0 + 32) * 1024 + kk + 64 + kl);
        }
        __syncthreads();
#pragma unroll
        for (int c32 = 0; c32 < 2; c32++) {
            s16x8 a[2], b[6];
#pragma unroll
            for (int rt = 0; rt < 2; rt++)
                a[rt] = *(const s16x8*)&As[wr * 32 + rt * 16 + m16][c32 * 32 + quad * 8];
#pragma unroll
            for (int ct = 0; ct < 6; ct++)
                b[ct] = *(const s16x8*)(Wt + (size_t)(wc * 96 + ct * 16 + m16) * 1024 + kk + c32 * 32 + quad * 8);
#pragma unroll
            for (int rt = 0; rt < 2; rt++)
#pragma unroll
                for (int ct = 0; ct < 6; ct++) acc[rt][ct] = MFMA16(a[rt], b[ct], acc[rt][ct]);
        }
        __syncthreads();
    }
#pragma unroll
    for (int p = 0; p < 2; p++) {
        if (wr == p) {
#pragma unroll
            for (int rt = 0; rt < 2; rt++)
#pragma unroll
                for (int ct = 0; ct < 6; ct++)
#pragma unroll
                    for (int rg = 0; rg < 4; rg++)
                        Cs[rt * 16 + quad * 4 + rg][wc * 96 + ct * 16 + m16] = f2bf(acc[rt][ct][rg]);
        }
        __syncthreads();
#pragma unroll
        for (int i = 0; i < 3; i++) {
            int id = tid + 512 * i;
            int row = id / 48, cc = id % 48;
            int col = cc * 8, mat = col >> 7, h = col & 127;
            s16x8 v = *(const s16x8*)&Cs[row][col];
            *(s16x8*)(QKV + (size_t)mat * 4194304 + ((size_t)(mt * 64 + p * 32 + row)) * 128 + h) = v;
        }
        __syncthreads();
    }
}

// ---------------- decode 480 blocks of (cfg, b, s, tile8) ----------------
__device__ __forceinline__ void decode_vt(int bid, int& c, int& b, int& s, int& t8) {
    int base;
    if (bid < 256)      { c = 0; base = 0; }
    else if (bid < 384) { c = 1; base = 256; }
    else if (bid < 448) { c = 2; base = 384; }
    else                { c = 3; base = 448; }
    int rem = bid - base;
    int sh = 6 - c;
    b = rem >> sh;
    int rr = rem & ((1 << sh) - 1);
    s = rr >> 3; t8 = rr & 7;
}

// ---------------- gather pass: tiled Vt for all cfgs + contiguous Kg for cfgs 1..3 ----------------
__global__ __launch_bounds__(256) void k_gather(const unsigned short* __restrict__ QKV, char* __restrict__ ws) {
    const unsigned short* K = QKV + (size_t)1 * 4194304;
    const unsigned short* V = QKV + (size_t)2 * 4194304;
    int bid = blockIdx.x, tid = threadIdx.x;
    if (bid < 480) {   // ---- Vt: gather + 8x8 register transpose; tiled [jt][128][64] ----
        int c, b, s, kb; decode_vt(bid, c, b, s, kb);
        const int S = 8 >> c, r = 1 << c, wseg = 1024 << c;
        const size_t vtoff[4] = {VT0_OFF, VT1_OFF, VT2_OFF, VT3_OFF};
        unsigned short* Vt = (unsigned short*)(ws + vtoff[c]) + ((size_t)(b * S + s)) * 131072;
        int kq8 = tid & 15, hq = tid >> 4;
        int key0 = kb * 128 + kq8 * 8;
        int jt = key0 >> 6, k0 = key0 & 63;
        s16x8 in[8];
#pragma unroll
        for (int i = 0; i < 8; i++) {
            int tok = s * wseg + (key0 + i) * r;
            in[i] = *(const s16x8*)(V + ((size_t)(b * 8192 + tok)) * 128 + hq * 8);
        }
#pragma unroll
        for (int jh = 0; jh < 8; jh++) {
            s16x8 o;
#pragma unroll
            for (int i = 0; i < 8; i++) o[i] = in[i][jh];
            *(s16x8*)(Vt + (size_t)jt * 8192 + (size_t)(hq * 8 + jh) * 64 + k0) = o;
        }
    } else {           // ---- Kg: row gather for c = 1..3 ----
        int r2 = bid - 480, c;
        if (r2 < 128)      { c = 1; }
        else if (r2 < 192) { c = 2; r2 -= 128; }
        else               { c = 3; r2 -= 192; }
        const int S = 8 >> c, r = 1 << c, wseg = 1024 << c;
        int b = r2 >> (6 - c);
        int rem = r2 & ((1 << (6 - c)) - 1);
        int s = rem >> 3, kb = rem & 7;
        const size_t kgoff[4] = {0, KG1_OFF, KG2_OFF, KG3_OFF};
        unsigned short* Kg = (unsigned short*)(ws + kgoff[c]) + ((size_t)(b * S + s)) * 131072;
        int row = tid >> 1, hh = (tid & 1) * 64;
        const unsigned short* src = K + ((size_t)(b * 8192 + s * wseg + (kb * 128 + row) * r)) * 128 + hh;
        unsigned short* dst = Kg + ((size_t)(kb * 128 + row)) * 128 + hh;
#pragma unroll
        for (int i = 0; i < 8; i++)
            *(s16x8*)(dst + i * 8) = *(const s16x8*)(src + i * 8);
    }
}

// ---------------- attention: paired q-tiles (p, 15-p), LDS-staged K/V, 3 blocks/CU ----------------
// grid 512: seg = bid & 63 (>=60 -> exit), pair p = bid >> 6. Same seg => same bid%8 => same XCD.
__global__ __launch_bounds__(256, 3) void k_attn(const unsigned short* __restrict__ QKV,
                                                 char* __restrict__ ws) {
    __shared__ s16x8 KsV[1024];              // [c4*4+quad][64 key] fragment-order, 16 KB
    __shared__ s16x8 VsV[1024];              // [kc*4+quad][128 h]  fragment-order, 16 KB
    __shared__ unsigned short Ps[128][72];   // P rows 0..63 low tile, 64..127 high; wave-private rows

    const int segid = blockIdx.x & 63;
    if (segid >= 60) return;
    const int p = blockIdx.x >> 6;           // pair index 0..7
    int c, b, s;
    if (segid < 32)      { c = 0; b = segid >> 3;        s = segid & 7; }
    else if (segid < 48) { c = 1; b = (segid - 32) >> 2; s = (segid - 32) & 3; }
    else if (segid < 56) { c = 2; b = (segid - 48) >> 1; s = (segid - 48) & 1; }
    else                 { c = 3; b = segid - 56;        s = 0; }
    const int S = 8 >> c, r = 1 << c, wseg = 1024 << c;
    const int segc = b * S + s;
    const int qtL = p, qtH = 15 - p, J = qtH + 1;

    const size_t vtoff[4] = {VT0_OFF, VT1_OFF, VT2_OFF, VT3_OFF};
    const size_t ooff[4]  = {O0_OFF, O1_OFF, O2_OFF, O3_OFF};
    const size_t loff[4]  = {L0_OFF, L1_OFF, L2_OFF, L3_OFF};
    const size_t kgoff[4] = {0, KG1_OFF, KG2_OFF, KG3_OFF};
    const unsigned short* Q  = QKV;
    const unsigned short* Kg = (c == 0)
        ? QKV + (size_t)1 * 4194304 + (size_t)segc * 131072
        : (const unsigned short*)(ws + kgoff[c]) + (size_t)segc * 131072;
    const unsigned short* Vt = (const unsigned short*)(ws + vtoff[c]) + (size_t)segc * 131072;
    float* Ob = (float*)(ws + ooff[c]) + (size_t)segc * 1024 * 128;
    float* Lb = (float*)(ws + loff[c]) + (size_t)segc * 1024;

    const int tid = threadIdx.x, lane = tid & 63, wv = tid >> 6;
    const int quad = lane >> 4, m16 = lane & 15;
    const float SCE = 0.08838834764831845f;  // 1/sqrt(128)

    // resident Q fragments: 16 low rows + 16 high rows per wave
    s16x8 qfL[4], qfH[4];
    {
        int tokL = s * wseg + (qtL * 64 + wv * 16 + m16) * r;
        int tokH = s * wseg + (qtH * 64 + wv * 16 + m16) * r;
        const unsigned short* qpL = Q + ((size_t)(b * 8192 + tokL)) * 128;
        const unsigned short* qpH = Q + ((size_t)(b * 8192 + tokH)) * 128;
#pragma unroll
        for (int c4 = 0; c4 < 4; c4++) {
            qfL[c4] = *(const s16x8*)(qpL + c4 * 32 + quad * 8);
            qfH[c4] = *(const s16x8*)(qpH + c4 * 32 + quad * 8);
        }
    }
    f32x4 oaccL[8], oaccH[8];
#pragma unroll
    for (int i = 0; i < 8; i++) { oaccL[i] = (f32x4)0.f; oaccH[i] = (f32x4)0.f; }
    float lsumL[4] = {}, lsumH[4] = {};

    for (int j = 0; j < J; j++) {
        // ---- stage K tile + V tile (32 x 1KB async copies, 8 per wave) ----
        const unsigned short* Kgt = Kg + (size_t)j * 8192;
        const unsigned short* Vtt = Vt + (size_t)j * 8192;
#pragma unroll
        for (int t = 0; t < 8; t++) {
            int id = wv * 8 + t;
            if (id < 16) {               // K: lane = key; [c4][qd][key][8]
                int c4 = id >> 2, qd = id & 3;
                GLOAD_LDS16(Kgt + (size_t)lane * 128 + c4 * 32 + qd * 8, &KsV[id * 64]);
            } else {                     // V: lane = h (within half); [kc][qd][h][8]
                int v = id - 16;
                int kc = v >> 3, qd = (v >> 1) & 3, hh = v & 1;
                GLOAD_LDS16(Vtt + (size_t)(hh * 64 + lane) * 64 + kc * 32 + qd * 8,
                            &VsV[(kc * 4 + qd) * 128 + hh * 64]);
            }
        }
        __syncthreads();

        const bool lowA = (j <= qtL);
        const bool dgL = (j == qtL), dgH = (j == qtH);
        const int rbase = wv * 16 + quad * 4;
        // ---- S = Q K^T, exp, P -> LDS (per 16-col slice to cap registers) ----
#pragma unroll
        for (int ct = 0; ct < 4; ct++) {
            f32x4 sL = (f32x4)0.f, sH = (f32x4)0.f;
#pragma unroll
            for (int c4 = 0; c4 < 4; c4++) {
                s16x8 kf = KsV[(c4 * 4 + quad) * 64 + ct * 16 + m16];
                if (lowA) sL = MFMA16(qfL[c4], kf, sL);
                sH = MFMA16(qfH[c4], kf, sH);
            }
            int colL = ct * 16 + m16;
            if (lowA) {
#pragma unroll
                for (int rg = 0; rg < 4; rg++) {
                    float pv = __expf(sL[rg] * SCE);
                    if (dgL && colL > rbase + rg) pv = 0.f;
                    lsumL[rg] += pv;
                    Ps[rbase + rg][colL] = f2bf(pv);
                }
            }
#pragma unroll
            for (int rg = 0; rg < 4; rg++) {
                float pv = __expf(sH[rg] * SCE);
                if (dgH && colL > rbase + rg) pv = 0.f;
                lsumH[rg] += pv;
                Ps[64 + rbase + rg][colL] = f2bf(pv);
            }
        }
        // ---- O += P V ----
#pragma unroll
        for (int kc = 0; kc < 2; kc++) {
            s16x8 aH = *(const s16x8*)&Ps[64 + wv * 16 + m16][kc * 32 + quad * 8];
            s16x8 aL;
            if (lowA) aL = *(const s16x8*)&Ps[wv * 16 + m16][kc * 32 + quad * 8];
#pragma unroll
            for (int nt = 0; nt < 8; nt++) {
                s16x8 bv = VsV[(kc * 4 + quad) * 128 + nt * 16 + m16];
                if (lowA) oaccL[nt] = MFMA16(aL, bv, oaccL[nt]);
                oaccH[nt] = MFMA16(aH, bv, oaccH[nt]);
            }
        }
        __syncthreads();
    }

    // ---- denominators: reduce across the 16 lanes sharing each row ----
#pragma unroll
    for (int rg = 0; rg < 4; rg++) {
        float vL = lsumL[rg], vH = lsumH[rg];
        vL += __shfl_xor(vL, 1); vL += __shfl_xor(vL, 2);
        vL += __shfl_xor(vL, 4); vL += __shfl_xor(vL, 8);
        vH += __shfl_xor(vH, 1); vH += __shfl_xor(vH, 2);
        vH += __shfl_xor(vH, 4); vH += __shfl_xor(vH, 8);
        lsumL[rg] = vL; lsumH[rg] = vH;
    }
    float* OcL = Ob + (size_t)(qtL * 64) * 128;
    float* OcH = Ob + (size_t)(qtH * 64) * 128;
#pragma unroll
    for (int nt = 0; nt < 8; nt++)
#pragma unroll
        for (int rg = 0; rg < 4; rg++) {
            int rl = wv * 16 + quad * 4 + rg;
            OcL[(size_t)rl * 128 + nt * 16 + m16] = oaccL[nt][rg];
            OcH[(size_t)rl * 128 + nt * 16 + m16] = oaccH[nt][rg];
        }
    if (m16 == 0) {
#pragma unroll
        for (int rg = 0; rg < 4; rg++) {
            int rl = wv * 16 + quad * 4 + rg;
            Lb[qtL * 64 + rl] = lsumL[rg];
            Lb[qtH * 64 + rl] = lsumH[rg];
        }
    }
}

// ---------------- cross-config combine: out = sum_c O_c / sum_c L_c ----------------
__global__ __launch_bounds__(256) void k_combine(const char* __restrict__ ws, float* __restrict__ out) {
    int gid = blockIdx.x * 256 + threadIdx.x;
    int rown = gid >> 5;
    int h4 = (gid & 31) * 4;
    int b = rown >> 13, n = rown & 8191;
    const size_t ooff[4] = {O0_OFF, O1_OFF, O2_OFF, O3_OFF};
    const size_t loff[4] = {L0_OFF, L1_OFF, L2_OFF, L3_OFF};
    float denom = 0.f;
    float4 acc = {0.f, 0.f, 0.f, 0.f};
#pragma unroll
    for (int c = 0; c < 4; c++) {
        if ((n & ((1 << c) - 1)) == 0) {
            int s = n >> (10 + c);
            int i = (n & ((1024 << c) - 1)) >> c;
            int rowc = b * (8192 >> c) + (s << 10) + i;
            denom += *((const float*)(ws + loff[c]) + rowc);
            const float4 o = *(const float4*)((const float*)(ws + ooff[c]) + (size_t)rowc * 128 + h4);
            acc.x += o.x; acc.y += o.y; acc.z += o.z; acc.w += o.w;
        }
    }
    float inv = 1.f / denom;
    float4 res = {acc.x * inv, acc.y * inv, acc.z * inv, acc.w * inv};
    *(float4*)(out + (size_t)rown * 128 + h4) = res;
}

extern "C" void kernel_launch(void* const* d_in, const int* in_sizes, int n_in,
                              void* d_out, int out_size, void* d_ws, size_t ws_size,
                              hipStream_t stream) {
    const float* x  = (const float*)d_in[0];
    const float* Wq = (const float*)d_in[1];
    const float* Wk = (const float*)d_in[2];
    const float* Wv = (const float*)d_in[3];
    char* ws = (char*)d_ws;
    unsigned short* Wt  = (unsigned short*)(ws + WT_OFF);
    unsigned short* QKV = (unsigned short*)(ws + QKV_OFF);

    k_wt<<<1536, 256, 0, stream>>>(Wq, Wk, Wv, Wt);
    k_qkv<<<512, 512, 0, stream>>>(x, Wt, QKV);
    k_gather<<<704, 256, 0, stream>>>(QKV, ws);
    k_attn<<<512, 256, 0, stream>>>(QKV, ws);
    k_combine<<<4096, 256, 0, stream>>>(ws, (float*)d_out);
}

// Round 4
// 306.175 us; speedup vs baseline: 1.6899x; 1.1384x over previous
//
#include <hip/hip_runtime.h>

typedef __attribute__((ext_vector_type(8))) short s16x8;
typedef __attribute__((ext_vector_type(4))) short s16x4;
typedef __attribute__((ext_vector_type(4))) float f32x4;

#define MFMA16(a,b,c) __builtin_amdgcn_mfma_f32_16x16x32_bf16((a),(b),(c),0,0,0)

// async global->LDS, 16B per lane; LDS dest is wave-uniform base + lane*16
#define GLOAD_LDS16(g, l) \
    __builtin_amdgcn_global_load_lds((const __attribute__((address_space(1))) void*)(g), \
                                     (__attribute__((address_space(3))) void*)(l), 16, 0, 0)

__device__ __forceinline__ unsigned short f2bf(float f) {
    unsigned u = __builtin_bit_cast(unsigned, f);
    u = (u + 0x7FFFu + ((u >> 16) & 1u)) >> 16;
    return (unsigned short)u;
}

// ---------------- ws layout (bytes), ~77.3 MB total ----------------
#define MB ((size_t)1 << 20)
#define WT_OFF   ((size_t)0)        // Wt[384][1024] bf16 (row = mat*128+h)
#define QKV_OFF  (1*MB)             // QKV[3][32768][128] bf16 = 24 MB
#define VT0_OFF  (25*MB)            // per-config V, TILED: [seg][16 jt][128 h][64 key] bf16
#define VT1_OFF  (33*MB)
#define VT2_OFF  (37*MB)
#define VT3_OFF  (39*MB)
#define KG1_OFF  (40*MB)            // per-config K gathered contig: [seg][1024 key][128 h]; c0 reads K directly
#define KG2_OFF  (44*MB)
#define KG3_OFF  (46*MB)
#define O0_OFF   (47*MB)            // per-config unnormalized O fp32 [seg*1024][128]
#define O1_OFF   (63*MB)
#define O2_OFF   (71*MB)
#define O3_OFF   (75*MB)
#define L0_OFF   (77*MB)            // per-config denominators fp32
#define L1_OFF   (L0_OFF + (size_t)131072)
#define L2_OFF   (L1_OFF + (size_t)65536)
#define L3_OFF   (L2_OFF + (size_t)32768)

// ---------------- W transpose: Wt[mat*128+h][c] = bf16(W[c][h]) ----------------
__global__ __launch_bounds__(256) void k_wt(const float* __restrict__ Wq, const float* __restrict__ Wk,
                                            const float* __restrict__ Wv, unsigned short* __restrict__ Wt) {
    int id = blockIdx.x * 256 + threadIdx.x;
    int mat = id >> 17;
    int rem = id & 131071;
    int h = rem >> 10, c = rem & 1023;
    const float* W = (mat == 0) ? Wq : (mat == 1) ? Wk : Wv;
    Wt[id] = f2bf(W[c * 128 + h]);
}

// ---------------- fused QKV GEMM, m97 structure ----------------
// grid (3, 256): blockIdx.x = N-tile = output matrix (Q/K/V), blockIdx.y = 128-row m-tile.
// 768 blocks = 3/CU co-resident. All staging via global_load_lds (x staged as fp32,
// converted to bf16 at fragment-read time). XOR-swizzled LDS: 2 lanes/bank on ds_read_b128.
__global__ __launch_bounds__(256, 3) void k_qkv(const float* __restrict__ x,
                                                const unsigned short* __restrict__ Wt,
                                                unsigned short* __restrict__ QKV) {
    union SMem {
        struct { float As[128][64]; unsigned short Bs[128][64]; } s;  // 32 KB + 16 KB
        unsigned short Cs[128][136];                                   // epilogue staging, 34 KB
    };
    __shared__ SMem sm;
    float* Asf = &sm.s.As[0][0];
    unsigned short* Bsu = &sm.s.Bs[0][0];

    const int nt = blockIdx.x;        // 0..2 == output matrix
    const int mt = blockIdx.y;        // 0..255
    const int tid = threadIdx.x, lane = tid & 63, wv = tid >> 6;
    const int quad = lane >> 4, m16 = lane & 15;
    const int row0 = (wv >> 1) * 64, col0 = (wv & 1) * 64;   // wave's 64x64 quadrant
    const float* xb = x + (size_t)mt * 128 * 1024;
    const unsigned short* Wb = Wt + (size_t)nt * 131072;

    f32x4 acc[4][4];
#pragma unroll
    for (int i = 0; i < 4; i++)
#pragma unroll
        for (int j = 0; j < 4; j++) acc[i][j] = (f32x4)0.f;

    for (int kk = 0; kk < 1024; kk += 64) {
        // ---- stage A (x, fp32): 32 KB = 32 insts, 8/wave. phys group = logical ^ (row&7) ----
#pragma unroll
        for (int t = 0; t < 8; t++) {
            int id = wv * 8 + t;                       // 0..31, wave-uniform
            int row = id * 4 + (lane >> 4);
            int gl = (lane & 15) ^ (row & 7);          // logical 16B-group this lane fetches
            GLOAD_LDS16(xb + (size_t)row * 1024 + kk + gl * 4, (char*)Asf + id * 1024);
        }
        // ---- stage B (Wt, bf16): 16 KB = 16 insts, 4/wave. phys group = logical ^ (col&7) ----
#pragma unroll
        for (int t = 0; t < 4; t++) {
            int id = wv * 4 + t;                       // 0..15
            int col = id * 8 + (lane >> 3);
            int gl = (lane & 7) ^ (lane >> 3);         // (col&7) == lane>>3 here
            GLOAD_LDS16(Wb + (size_t)col * 1024 + kk + gl * 8, (char*)Bsu + id * 1024);
        }
        __syncthreads();
        // ---- compute: 2 x 16 MFMA ----
#pragma unroll
        for (int c32 = 0; c32 < 2; c32++) {
            s16x8 a[4], b[4];
#pragma unroll
            for (int rt = 0; rt < 4; rt++) {
                int row = row0 + rt * 16 + m16;
                int g0 = c32 * 8 + quad * 2;
                float4 lo = *(const float4*)&Asf[row * 64 + ((g0 ^ (row & 7)) << 2)];
                float4 hi = *(const float4*)&Asf[row * 64 + (((g0 + 1) ^ (row & 7)) << 2)];
                s16x8 av;
                av[0] = (short)f2bf(lo.x); av[1] = (short)f2bf(lo.y);
                av[2] = (short)f2bf(lo.z); av[3] = (short)f2bf(lo.w);
                av[4] = (short)f2bf(hi.x); av[5] = (short)f2bf(hi.y);
                av[6] = (short)f2bf(hi.z); av[7] = (short)f2bf(hi.w);
                a[rt] = av;
            }
#pragma unroll
            for (int ct = 0; ct < 4; ct++) {
                int col = col0 + ct * 16 + m16;
                b[ct] = *(const s16x8*)&Bsu[col * 64 + (((c32 * 4 + quad) ^ (col & 7)) << 3)];
            }
#pragma unroll
            for (int rt = 0; rt < 4; rt++)
#pragma unroll
                for (int ct = 0; ct < 4; ct++) acc[rt][ct] = MFMA16(a[rt], b[ct], acc[rt][ct]);
        }
        __syncthreads();
    }

    // ---- epilogue: C-layout -> LDS (reuse As/Bs) -> coalesced 16B stores ----
#pragma unroll
    for (int rt = 0; rt < 4; rt++)
#pragma unroll
        for (int ct = 0; ct < 4; ct++)
#pragma unroll
            for (int rg = 0; rg < 4; rg++)
                sm.Cs[row0 + rt * 16 + quad * 4 + rg][col0 + ct * 16 + m16] = f2bf(acc[rt][ct][rg]);
    __syncthreads();
    unsigned short* Out = QKV + (size_t)nt * 4194304 + (size_t)mt * 128 * 128;
#pragma unroll
    for (int i = 0; i < 8; i++) {
        int id = tid + 256 * i;
        int row = id >> 4, oc = id & 15;
        *(s16x8*)(Out + (size_t)row * 128 + oc * 8) = *(const s16x8*)&sm.Cs[row][oc * 8];
    }
}

// ---------------- decode 480 blocks of (cfg, b, s, tile8) ----------------
__device__ __forceinline__ void decode_vt(int bid, int& c, int& b, int& s, int& t8) {
    int base;
    if (bid < 256)      { c = 0; base = 0; }
    else if (bid < 384) { c = 1; base = 256; }
    else if (bid < 448) { c = 2; base = 384; }
    else                { c = 3; base = 448; }
    int rem = bid - base;
    int sh = 6 - c;
    b = rem >> sh;
    int rr = rem & ((1 << sh) - 1);
    s = rr >> 3; t8 = rr & 7;
}

// ---------------- gather pass: tiled Vt for all cfgs + contiguous Kg for cfgs 1..3 ----------------
__global__ __launch_bounds__(256) void k_gather(const unsigned short* __restrict__ QKV, char* __restrict__ ws) {
    const unsigned short* K = QKV + (size_t)1 * 4194304;
    const unsigned short* V = QKV + (size_t)2 * 4194304;
    int bid = blockIdx.x, tid = threadIdx.x;
    if (bid < 480) {   // ---- Vt: gather + 8x8 register transpose; tiled [jt][128][64] ----
        int c, b, s, kb; decode_vt(bid, c, b, s, kb);
        const int S = 8 >> c, r = 1 << c, wseg = 1024 << c;
        const size_t vtoff[4] = {VT0_OFF, VT1_OFF, VT2_OFF, VT3_OFF};
        unsigned short* Vt = (unsigned short*)(ws + vtoff[c]) + ((size_t)(b * S + s)) * 131072;
        int kq8 = tid & 15, hq = tid >> 4;
        int key0 = kb * 128 + kq8 * 8;
        int jt = key0 >> 6, k0 = key0 & 63;
        s16x8 in[8];
#pragma unroll
        for (int i = 0; i < 8; i++) {
            int tok = s * wseg + (key0 + i) * r;
            in[i] = *(const s16x8*)(V + ((size_t)(b * 8192 + tok)) * 128 + hq * 8);
        }
#pragma unroll
        for (int jh = 0; jh < 8; jh++) {
            s16x8 o;
#pragma unroll
            for (int i = 0; i < 8; i++) o[i] = in[i][jh];
            *(s16x8*)(Vt + (size_t)jt * 8192 + (size_t)(hq * 8 + jh) * 64 + k0) = o;
        }
    } else {           // ---- Kg: row gather for c = 1..3 ----
        int r2 = bid - 480, c;
        if (r2 < 128)      { c = 1; }
        else if (r2 < 192) { c = 2; r2 -= 128; }
        else               { c = 3; r2 -= 192; }
        const int S = 8 >> c, r = 1 << c, wseg = 1024 << c;
        int b = r2 >> (6 - c);
        int rem = r2 & ((1 << (6 - c)) - 1);
        int s = rem >> 3, kb = rem & 7;
        const size_t kgoff[4] = {0, KG1_OFF, KG2_OFF, KG3_OFF};
        unsigned short* Kg = (unsigned short*)(ws + kgoff[c]) + ((size_t)(b * S + s)) * 131072;
        int row = tid >> 1, hh = (tid & 1) * 64;
        const unsigned short* src = K + ((size_t)(b * 8192 + s * wseg + (kb * 128 + row) * r)) * 128 + hh;
        unsigned short* dst = Kg + ((size_t)(kb * 128 + row)) * 128 + hh;
#pragma unroll
        for (int i = 0; i < 8; i++)
            *(s16x8*)(dst + i * 8) = *(const s16x8*)(src + i * 8);
    }
}

// ---------------- attention: paired q-tiles (p, 15-p), LDS-staged K/V, 3 blocks/CU ----------------
__global__ __launch_bounds__(256, 3) void k_attn(const unsigned short* __restrict__ QKV,
                                                 char* __restrict__ ws) {
    __shared__ s16x8 KsV[1024];              // [c4*4+quad][64 key] fragment-order, 16 KB
    __shared__ s16x8 VsV[1024];              // [kc*4+quad][128 h]  fragment-order, 16 KB
    __shared__ unsigned short Ps[128][72];   // P rows 0..63 low tile, 64..127 high; wave-private rows

    const int segid = blockIdx.x & 63;
    if (segid >= 60) return;
    const int p = blockIdx.x >> 6;           // pair index 0..7
    int c, b, s;
    if (segid < 32)      { c = 0; b = segid >> 3;        s = segid & 7; }
    else if (segid < 48) { c = 1; b = (segid - 32) >> 2; s = (segid - 32) & 3; }
    else if (segid < 56) { c = 2; b = (segid - 48) >> 1; s = (segid - 48) & 1; }
    else                 { c = 3; b = segid - 56;        s = 0; }
    const int S = 8 >> c, r = 1 << c, wseg = 1024 << c;
    const int segc = b * S + s;
    const int qtL = p, qtH = 15 - p, J = qtH + 1;

    const size_t vtoff[4] = {VT0_OFF, VT1_OFF, VT2_OFF, VT3_OFF};
    const size_t ooff[4]  = {O0_OFF, O1_OFF, O2_OFF, O3_OFF};
    const size_t loff[4]  = {L0_OFF, L1_OFF, L2_OFF, L3_OFF};
    const size_t kgoff[4] = {0, KG1_OFF, KG2_OFF, KG3_OFF};
    const unsigned short* Q  = QKV;
    const unsigned short* Kg = (c == 0)
        ? QKV + (size_t)1 * 4194304 + (size_t)segc * 131072
        : (const unsigned short*)(ws + kgoff[c]) + (size_t)segc * 131072;
    const unsigned short* Vt = (const unsigned short*)(ws + vtoff[c]) + (size_t)segc * 131072;
    float* Ob = (float*)(ws + ooff[c]) + (size_t)segc * 1024 * 128;
    float* Lb = (float*)(ws + loff[c]) + (size_t)segc * 1024;

    const int tid = threadIdx.x, lane = tid & 63, wv = tid >> 6;
    const int quad = lane >> 4, m16 = lane & 15;
    const float SCE = 0.08838834764831845f;  // 1/sqrt(128)

    s16x8 qfL[4], qfH[4];
    {
        int tokL = s * wseg + (qtL * 64 + wv * 16 + m16) * r;
        int tokH = s * wseg + (qtH * 64 + wv * 16 + m16) * r;
        const unsigned short* qpL = Q + ((size_t)(b * 8192 + tokL)) * 128;
        const unsigned short* qpH = Q + ((size_t)(b * 8192 + tokH)) * 128;
#pragma unroll
        for (int c4 = 0; c4 < 4; c4++) {
            qfL[c4] = *(const s16x8*)(qpL + c4 * 32 + quad * 8);
            qfH[c4] = *(const s16x8*)(qpH + c4 * 32 + quad * 8);
        }
    }
    f32x4 oaccL[8], oaccH[8];
#pragma unroll
    for (int i = 0; i < 8; i++) { oaccL[i] = (f32x4)0.f; oaccH[i] = (f32x4)0.f; }
    float lsumL[4] = {}, lsumH[4] = {};

    for (int j = 0; j < J; j++) {
        const unsigned short* Kgt = Kg + (size_t)j * 8192;
        const unsigned short* Vtt = Vt + (size_t)j * 8192;
#pragma unroll
        for (int t = 0; t < 8; t++) {
            int id = wv * 8 + t;
            if (id < 16) {               // K: lane = key; [c4][qd][key][8]
                int c4 = id >> 2, qd = id & 3;
                GLOAD_LDS16(Kgt + (size_t)lane * 128 + c4 * 32 + qd * 8, &KsV[id * 64]);
            } else {                     // V: lane = h (within half); [kc][qd][h][8]
                int v = id - 16;
                int kc = v >> 3, qd = (v >> 1) & 3, hh = v & 1;
                GLOAD_LDS16(Vtt + (size_t)(hh * 64 + lane) * 64 + kc * 32 + qd * 8,
                            &VsV[(kc * 4 + qd) * 128 + hh * 64]);
            }
        }
        __syncthreads();

        const bool lowA = (j <= qtL);
        const bool dgL = (j == qtL), dgH = (j == qtH);
        const int rbase = wv * 16 + quad * 4;
#pragma unroll
        for (int ct = 0; ct < 4; ct++) {
            f32x4 sL = (f32x4)0.f, sH = (f32x4)0.f;
#pragma unroll
            for (int c4 = 0; c4 < 4; c4++) {
                s16x8 kf = KsV[(c4 * 4 + quad) * 64 + ct * 16 + m16];
                if (lowA) sL = MFMA16(qfL[c4], kf, sL);
                sH = MFMA16(qfH[c4], kf, sH);
            }
            int colL = ct * 16 + m16;
            if (lowA) {
#pragma unroll
                for (int rg = 0; rg < 4; rg++) {
                    float pv = __expf(sL[rg] * SCE);
                    if (dgL && colL > rbase + rg) pv = 0.f;
                    lsumL[rg] += pv;
                    Ps[rbase + rg][colL] = f2bf(pv);
                }
            }
#pragma unroll
            for (int rg = 0; rg < 4; rg++) {
                float pv = __expf(sH[rg] * SCE);
                if (dgH && colL > rbase + rg) pv = 0.f;
                lsumH[rg] += pv;
                Ps[64 + rbase + rg][colL] = f2bf(pv);
            }
        }
#pragma unroll
        for (int kc = 0; kc < 2; kc++) {
            s16x8 aH = *(const s16x8*)&Ps[64 + wv * 16 + m16][kc * 32 + quad * 8];
            s16x8 aL;
            if (lowA) aL = *(const s16x8*)&Ps[wv * 16 + m16][kc * 32 + quad * 8];
#pragma unroll
            for (int nt = 0; nt < 8; nt++) {
                s16x8 bv = VsV[(kc * 4 + quad) * 128 + nt * 16 + m16];
                if (lowA) oaccL[nt] = MFMA16(aL, bv, oaccL[nt]);
                oaccH[nt] = MFMA16(aH, bv, oaccH[nt]);
            }
        }
        __syncthreads();
    }

#pragma unroll
    for (int rg = 0; rg < 4; rg++) {
        float vL = lsumL[rg], vH = lsumH[rg];
        vL += __shfl_xor(vL, 1); vL += __shfl_xor(vL, 2);
        vL += __shfl_xor(vL, 4); vL += __shfl_xor(vL, 8);
        vH += __shfl_xor(vH, 1); vH += __shfl_xor(vH, 2);
        vH += __shfl_xor(vH, 4); vH += __shfl_xor(vH, 8);
        lsumL[rg] = vL; lsumH[rg] = vH;
    }
    float* OcL = Ob + (size_t)(qtL * 64) * 128;
    float* OcH = Ob + (size_t)(qtH * 64) * 128;
#pragma unroll
    for (int nt = 0; nt < 8; nt++)
#pragma unroll
        for (int rg = 0; rg < 4; rg++) {
            int rl = wv * 16 + quad * 4 + rg;
            OcL[(size_t)rl * 128 + nt * 16 + m16] = oaccL[nt][rg];
            OcH[(size_t)rl * 128 + nt * 16 + m16] = oaccH[nt][rg];
        }
    if (m16 == 0) {
#pragma unroll
        for (int rg = 0; rg < 4; rg++) {
            int rl = wv * 16 + quad * 4 + rg;
            Lb[qtL * 64 + rl] = lsumL[rg];
            Lb[qtH * 64 + rl] = lsumH[rg];
        }
    }
}

// ---------------- cross-config combine: out = sum_c O_c / sum_c L_c ----------------
__global__ __launch_bounds__(256) void k_combine(const char* __restrict__ ws, float* __restrict__ out) {
    int gid = blockIdx.x * 256 + threadIdx.x;
    int rown = gid >> 5;
    int h4 = (gid & 31) * 4;
    int b = rown >> 13, n = rown & 8191;
    const size_t ooff[4] = {O0_OFF, O1_OFF, O2_OFF, O3_OFF};
    const size_t loff[4] = {L0_OFF, L1_OFF, L2_OFF, L3_OFF};
    float denom = 0.f;
    float4 acc = {0.f, 0.f, 0.f, 0.f};
#pragma unroll
    for (int c = 0; c < 4; c++) {
        if ((n & ((1 << c) - 1)) == 0) {
            int s = n >> (10 + c);
            int i = (n & ((1024 << c) - 1)) >> c;
            int rowc = b * (8192 >> c) + (s << 10) + i;
            denom += *((const float*)(ws + loff[c]) + rowc);
            const float4 o = *(const float4*)((const float*)(ws + ooff[c]) + (size_t)rowc * 128 + h4);
            acc.x += o.x; acc.y += o.y; acc.z += o.z; acc.w += o.w;
        }
    }
    float inv = 1.f / denom;
    float4 res = {acc.x * inv, acc.y * inv, acc.z * inv, acc.w * inv};
    *(float4*)(out + (size_t)rown * 128 + h4) = res;
}

extern "C" void kernel_launch(void* const* d_in, const int* in_sizes, int n_in,
                              void* d_out, int out_size, void* d_ws, size_t ws_size,
                              hipStream_t stream) {
    const float* x  = (const float*)d_in[0];
    const float* Wq = (const float*)d_in[1];
    const float* Wk = (const float*)d_in[2];
    const float* Wv = (const float*)d_in[3];
    char* ws = (char*)d_ws;
    unsigned short* Wt  = (unsigned short*)(ws + WT_OFF);
    unsigned short* QKV = (unsigned short*)(ws + QKV_OFF);

    k_wt<<<1536, 256, 0, stream>>>(Wq, Wk, Wv, Wt);
    k_qkv<<<dim3(3, 256), 256, 0, stream>>>(x, Wt, QKV);
    k_gather<<<704, 256, 0, stream>>>(QKV, ws);
    k_attn<<<512, 256, 0, stream>>>(QKV, ws);
    k_combine<<<4096, 256, 0, stream>>>(ws, (float*)d_out);
}

// Round 5
// 297.063 us; speedup vs baseline: 1.7418x; 1.0307x over previous
//
#include <hip/hip_runtime.h>

typedef __attribute__((ext_vector_type(8))) short s16x8;
typedef __attribute__((ext_vector_type(4))) short s16x4;
typedef __attribute__((ext_vector_type(4))) float f32x4;

#define MFMA16(a,b,c) __builtin_amdgcn_mfma_f32_16x16x32_bf16((a),(b),(c),0,0,0)

// async global->LDS, 16B per lane; LDS dest is wave-uniform base + lane*16
#define GLOAD_LDS16(g, l) \
    __builtin_amdgcn_global_load_lds((const __attribute__((address_space(1))) void*)(g), \
                                     (__attribute__((address_space(3))) void*)(l), 16, 0, 0)

__device__ __forceinline__ unsigned short f2bf(float f) {
    unsigned u = __builtin_bit_cast(unsigned, f);
    u = (u + 0x7FFFu + ((u >> 16) & 1u)) >> 16;
    return (unsigned short)u;
}

// ---------------- ws layout (bytes), ~77.3 MB total ----------------
#define MB ((size_t)1 << 20)
#define WT_OFF   ((size_t)0)        // Wt[384][1024] bf16 (row = mat*128+h)
#define QKV_OFF  (1*MB)             // QKV[3][32768][128] bf16 = 24 MB
#define VT0_OFF  (25*MB)            // per-config V, TILED: [seg][16 jt][128 h][64 key] bf16
#define VT1_OFF  (33*MB)
#define VT2_OFF  (37*MB)
#define VT3_OFF  (39*MB)
#define KG1_OFF  (40*MB)            // per-config K gathered contig: [seg][1024 key][128 h]; c0 reads K directly
#define KG2_OFF  (44*MB)
#define KG3_OFF  (46*MB)
#define O0_OFF   (47*MB)            // per-config unnormalized O fp32 [seg*1024][128]
#define O1_OFF   (63*MB)
#define O2_OFF   (71*MB)
#define O3_OFF   (75*MB)
#define L0_OFF   (77*MB)            // per-config denominators fp32
#define L1_OFF   (L0_OFF + (size_t)131072)
#define L2_OFF   (L1_OFF + (size_t)65536)
#define L3_OFF   (L2_OFF + (size_t)32768)

// ---------------- W transpose: Wt[mat*128+h][c] = bf16(W[c][h]) ----------------
__global__ __launch_bounds__(256) void k_wt(const float* __restrict__ Wq, const float* __restrict__ Wk,
                                            const float* __restrict__ Wv, unsigned short* __restrict__ Wt) {
    int id = blockIdx.x * 256 + threadIdx.x;
    int mat = id >> 17;
    int rem = id & 131071;
    int h = rem >> 10, c = rem & 1023;
    const float* W = (mat == 0) ? Wq : (mat == 1) ? Wk : Wv;
    Wt[id] = f2bf(W[c * 128 + h]);
}

// ---------------- fused QKV GEMM: [32768 x 1024] @ [1024 x 384], x read from HBM EXACTLY once ----
// 512 blocks of 64 rows x 384 cols (all 3 matrices). Waves 2x2: wave = 32 rows x 192 cols.
// A staged as fp32 via global_load_lds (bf16 convert at fragment read); B (Wt) staged bf16,
// L2-resident (768 KB footprint). XOR-swizzled LDS -> 2 lanes/bank on all ds_read_b128.
__global__ __launch_bounds__(256, 2) void k_qkv(const float* __restrict__ x,
                                                const unsigned short* __restrict__ Wt,
                                                unsigned short* __restrict__ QKV) {
    union SMem {
        struct { float As[64][64]; unsigned short Bs[384][64]; } s;  // 16 KB + 48 KB
        unsigned short Cs[64][392];                                   // epilogue staging, 49 KB
    };
    __shared__ SMem sm;
    float* Asf = &sm.s.As[0][0];
    unsigned short* Bsu = &sm.s.Bs[0][0];

    const int mt = blockIdx.x;        // 0..511, 64-row m-tile
    const int tid = threadIdx.x, lane = tid & 63, wv = tid >> 6;
    const int quad = lane >> 4, m16 = lane & 15;
    const int wr = wv >> 1, wc = wv & 1;     // wave tile: rows wr*32.., cols wc*192..
    const float* xb = x + (size_t)mt * 64 * 1024;

    f32x4 acc[2][12];
#pragma unroll
    for (int i = 0; i < 2; i++)
#pragma unroll
        for (int j = 0; j < 12; j++) acc[i][j] = (f32x4)0.f;

    for (int kk = 0; kk < 1024; kk += 64) {
        // ---- stage A (x, fp32): 16 KB = 16 insts, 4/wave. phys group = logical ^ (row&7) ----
#pragma unroll
        for (int t = 0; t < 4; t++) {
            int id = wv * 4 + t;                       // 0..15, wave-uniform
            int row = id * 4 + (lane >> 4);
            int gl = (lane & 15) ^ (row & 7);          // logical 16B-group this lane fetches
            GLOAD_LDS16(xb + (size_t)row * 1024 + kk + gl * 4, (char*)Asf + id * 1024);
        }
        // ---- stage B (Wt, bf16): 48 KB = 48 insts, 12/wave. phys group = logical ^ (col&7) ----
#pragma unroll
        for (int t = 0; t < 12; t++) {
            int id = wv * 12 + t;                      // 0..47
            int col = id * 8 + (lane >> 3);
            int gl = (lane & 7) ^ (lane >> 3);         // (col&7) == lane>>3 here
            GLOAD_LDS16(Wt + (size_t)col * 1024 + kk + gl * 8, (char*)Bsu + id * 1024);
        }
        __syncthreads();
        // ---- compute: 2 x 24 MFMA ----
#pragma unroll
        for (int c32 = 0; c32 < 2; c32++) {
            s16x8 a[2], b[12];
#pragma unroll
            for (int rt = 0; rt < 2; rt++) {
                int row = wr * 32 + rt * 16 + m16;
                int g0 = c32 * 8 + quad * 2;
                float4 lo = *(const float4*)&Asf[row * 64 + ((g0 ^ (row & 7)) << 2)];
                float4 hi = *(const float4*)&Asf[row * 64 + (((g0 + 1) ^ (row & 7)) << 2)];
                s16x8 av;
                av[0] = (short)f2bf(lo.x); av[1] = (short)f2bf(lo.y);
                av[2] = (short)f2bf(lo.z); av[3] = (short)f2bf(lo.w);
                av[4] = (short)f2bf(hi.x); av[5] = (short)f2bf(hi.y);
                av[6] = (short)f2bf(hi.z); av[7] = (short)f2bf(hi.w);
                a[rt] = av;
            }
#pragma unroll
            for (int ct = 0; ct < 12; ct++) {
                int col = wc * 192 + ct * 16 + m16;
                b[ct] = *(const s16x8*)&Bsu[col * 64 + (((c32 * 4 + quad) ^ (col & 7)) << 3)];
            }
#pragma unroll
            for (int rt = 0; rt < 2; rt++)
#pragma unroll
                for (int ct = 0; ct < 12; ct++) acc[rt][ct] = MFMA16(a[rt], b[ct], acc[rt][ct]);
        }
        __syncthreads();
    }

    // ---- epilogue: C-layout -> LDS (reuse As/Bs) -> coalesced 16B stores ----
#pragma unroll
    for (int rt = 0; rt < 2; rt++)
#pragma unroll
        for (int ct = 0; ct < 12; ct++)
#pragma unroll
            for (int rg = 0; rg < 4; rg++)
                sm.Cs[wr * 32 + rt * 16 + quad * 4 + rg][wc * 192 + ct * 16 + m16] = f2bf(acc[rt][ct][rg]);
    __syncthreads();
#pragma unroll
    for (int i = 0; i < 12; i++) {
        int id = tid + 256 * i;                 // 0..3071 -> 64 rows x 48 col-chunks
        int row = id / 48, cc = id % 48;
        int col = cc * 8, mat = col >> 7, h = col & 127;
        *(s16x8*)(QKV + (size_t)mat * 4194304 + ((size_t)(mt * 64 + row)) * 128 + h) =
            *(const s16x8*)&sm.Cs[row][col];
    }
}

// ---------------- decode 480 blocks of (cfg, b, s, tile8) ----------------
__device__ __forceinline__ void decode_vt(int bid, int& c, int& b, int& s, int& t8) {
    int base;
    if (bid < 256)      { c = 0; base = 0; }
    else if (bid < 384) { c = 1; base = 256; }
    else if (bid < 448) { c = 2; base = 384; }
    else                { c = 3; base = 448; }
    int rem = bid - base;
    int sh = 6 - c;
    b = rem >> sh;
    int rr = rem & ((1 << sh) - 1);
    s = rr >> 3; t8 = rr & 7;
}

// ---------------- gather pass: tiled Vt for all cfgs + contiguous Kg for cfgs 1..3 ----------------
__global__ __launch_bounds__(256) void k_gather(const unsigned short* __restrict__ QKV, char* __restrict__ ws) {
    const unsigned short* K = QKV + (size_t)1 * 4194304;
    const unsigned short* V = QKV + (size_t)2 * 4194304;
    int bid = blockIdx.x, tid = threadIdx.x;
    if (bid < 480) {   // ---- Vt: gather + 8x8 register transpose; tiled [jt][128][64] ----
        int c, b, s, kb; decode_vt(bid, c, b, s, kb);
        const int S = 8 >> c, r = 1 << c, wseg = 1024 << c;
        const size_t vtoff[4] = {VT0_OFF, VT1_OFF, VT2_OFF, VT3_OFF};
        unsigned short* Vt = (unsigned short*)(ws + vtoff[c]) + ((size_t)(b * S + s)) * 131072;
        int kq8 = tid & 15, hq = tid >> 4;
        int key0 = kb * 128 + kq8 * 8;
        int jt = key0 >> 6, k0 = key0 & 63;
        s16x8 in[8];
#pragma unroll
        for (int i = 0; i < 8; i++) {
            int tok = s * wseg + (key0 + i) * r;
            in[i] = *(const s16x8*)(V + ((size_t)(b * 8192 + tok)) * 128 + hq * 8);
        }
#pragma unroll
        for (int jh = 0; jh < 8; jh++) {
            s16x8 o;
#pragma unroll
            for (int i = 0; i < 8; i++) o[i] = in[i][jh];
            *(s16x8*)(Vt + (size_t)jt * 8192 + (size_t)(hq * 8 + jh) * 64 + k0) = o;
        }
    } else {           // ---- Kg: row gather for c = 1..3 ----
        int r2 = bid - 480, c;
        if (r2 < 128)      { c = 1; }
        else if (r2 < 192) { c = 2; r2 -= 128; }
        else               { c = 3; r2 -= 192; }
        const int S = 8 >> c, r = 1 << c, wseg = 1024 << c;
        int b = r2 >> (6 - c);
        int rem = r2 & ((1 << (6 - c)) - 1);
        int s = rem >> 3, kb = rem & 7;
        const size_t kgoff[4] = {0, KG1_OFF, KG2_OFF, KG3_OFF};
        unsigned short* Kg = (unsigned short*)(ws + kgoff[c]) + ((size_t)(b * S + s)) * 131072;
        int row = tid >> 1, hh = (tid & 1) * 64;
        const unsigned short* src = K + ((size_t)(b * 8192 + s * wseg + (kb * 128 + row) * r)) * 128 + hh;
        unsigned short* dst = Kg + ((size_t)(kb * 128 + row)) * 128 + hh;
#pragma unroll
        for (int i = 0; i < 8; i++)
            *(s16x8*)(dst + i * 8) = *(const s16x8*)(src + i * 8);
    }
}

// ---------------- attention: paired q-tiles (p, 15-p), LDS-staged K/V, 3 blocks/CU ----------------
__global__ __launch_bounds__(256, 3) void k_attn(const unsigned short* __restrict__ QKV,
                                                 char* __restrict__ ws) {
    __shared__ s16x8 KsV[1024];              // [c4*4+quad][64 key] fragment-order, 16 KB
    __shared__ s16x8 VsV[1024];              // [kc*4+quad][128 h]  fragment-order, 16 KB
    __shared__ unsigned short Ps[128][72];   // P rows 0..63 low tile, 64..127 high; wave-private rows

    const int segid = blockIdx.x & 63;
    if (segid >= 60) return;
    const int p = blockIdx.x >> 6;           // pair index 0..7
    int c, b, s;
    if (segid < 32)      { c = 0; b = segid >> 3;        s = segid & 7; }
    else if (segid < 48) { c = 1; b = (segid - 32) >> 2; s = (segid - 32) & 3; }
    else if (segid < 56) { c = 2; b = (segid - 48) >> 1; s = (segid - 48) & 1; }
    else                 { c = 3; b = segid - 56;        s = 0; }
    const int S = 8 >> c, r = 1 << c, wseg = 1024 << c;
    const int segc = b * S + s;
    const int qtL = p, qtH = 15 - p, J = qtH + 1;

    const size_t vtoff[4] = {VT0_OFF, VT1_OFF, VT2_OFF, VT3_OFF};
    const size_t ooff[4]  = {O0_OFF, O1_OFF, O2_OFF, O3_OFF};
    const size_t loff[4]  = {L0_OFF, L1_OFF, L2_OFF, L3_OFF};
    const size_t kgoff[4] = {0, KG1_OFF, KG2_OFF, KG3_OFF};
    const unsigned short* Q  = QKV;
    const unsigned short* Kg = (c == 0)
        ? QKV + (size_t)1 * 4194304 + (size_t)segc * 131072
        : (const unsigned short*)(ws + kgoff[c]) + (size_t)segc * 131072;
    const unsigned short* Vt = (const unsigned short*)(ws + vtoff[c]) + (size_t)segc * 131072;
    float* Ob = (float*)(ws + ooff[c]) + (size_t)segc * 1024 * 128;
    float* Lb = (float*)(ws + loff[c]) + (size_t)segc * 1024;

    const int tid = threadIdx.x, lane = tid & 63, wv = tid >> 6;
    const int quad = lane >> 4, m16 = lane & 15;
    const float SCE = 0.08838834764831845f;  // 1/sqrt(128)

    s16x8 qfL[4], qfH[4];
    {
        int tokL = s * wseg + (qtL * 64 + wv * 16 + m16) * r;
        int tokH = s * wseg + (qtH * 64 + wv * 16 + m16) * r;
        const unsigned short* qpL = Q + ((size_t)(b * 8192 + tokL)) * 128;
        const unsigned short* qpH = Q + ((size_t)(b * 8192 + tokH)) * 128;
#pragma unroll
        for (int c4 = 0; c4 < 4; c4++) {
            qfL[c4] = *(const s16x8*)(qpL + c4 * 32 + quad * 8);
            qfH[c4] = *(const s16x8*)(qpH + c4 * 32 + quad * 8);
        }
    }
    f32x4 oaccL[8], oaccH[8];
#pragma unroll
    for (int i = 0; i < 8; i++) { oaccL[i] = (f32x4)0.f; oaccH[i] = (f32x4)0.f; }
    float lsumL[4] = {}, lsumH[4] = {};

    for (int j = 0; j < J; j++) {
        const unsigned short* Kgt = Kg + (size_t)j * 8192;
        const unsigned short* Vtt = Vt + (size_t)j * 8192;
#pragma unroll
        for (int t = 0; t < 8; t++) {
            int id = wv * 8 + t;
            if (id < 16) {               // K: lane = key; [c4][qd][key][8]
                int c4 = id >> 2, qd = id & 3;
                GLOAD_LDS16(Kgt + (size_t)lane * 128 + c4 * 32 + qd * 8, &KsV[id * 64]);
            } else {                     // V: lane = h (within half); [kc][qd][h][8]
                int v = id - 16;
                int kc = v >> 3, qd = (v >> 1) & 3, hh = v & 1;
                GLOAD_LDS16(Vtt + (size_t)(hh * 64 + lane) * 64 + kc * 32 + qd * 8,
                            &VsV[(kc * 4 + qd) * 128 + hh * 64]);
            }
        }
        __syncthreads();

        const bool lowA = (j <= qtL);
        const bool dgL = (j == qtL), dgH = (j == qtH);
        const int rbase = wv * 16 + quad * 4;
#pragma unroll
        for (int ct = 0; ct < 4; ct++) {
            f32x4 sL = (f32x4)0.f, sH = (f32x4)0.f;
#pragma unroll
            for (int c4 = 0; c4 < 4; c4++) {
                s16x8 kf = KsV[(c4 * 4 + quad) * 64 + ct * 16 + m16];
                if (lowA) sL = MFMA16(qfL[c4], kf, sL);
                sH = MFMA16(qfH[c4], kf, sH);
            }
            int colL = ct * 16 + m16;
            if (lowA) {
#pragma unroll
                for (int rg = 0; rg < 4; rg++) {
                    float pv = __expf(sL[rg] * SCE);
                    if (dgL && colL > rbase + rg) pv = 0.f;
                    lsumL[rg] += pv;
                    Ps[rbase + rg][colL] = f2bf(pv);
                }
            }
#pragma unroll
            for (int rg = 0; rg < 4; rg++) {
                float pv = __expf(sH[rg] * SCE);
                if (dgH && colL > rbase + rg) pv = 0.f;
                lsumH[rg] += pv;
                Ps[64 + rbase + rg][colL] = f2bf(pv);
            }
        }
#pragma unroll
        for (int kc = 0; kc < 2; kc++) {
            s16x8 aH = *(const s16x8*)&Ps[64 + wv * 16 + m16][kc * 32 + quad * 8];
            s16x8 aL;
            if (lowA) aL = *(const s16x8*)&Ps[wv * 16 + m16][kc * 32 + quad * 8];
#pragma unroll
            for (int nt = 0; nt < 8; nt++) {
                s16x8 bv = VsV[(kc * 4 + quad) * 128 + nt * 16 + m16];
                if (lowA) oaccL[nt] = MFMA16(aL, bv, oaccL[nt]);
                oaccH[nt] = MFMA16(aH, bv, oaccH[nt]);
            }
        }
        __syncthreads();
    }

#pragma unroll
    for (int rg = 0; rg < 4; rg++) {
        float vL = lsumL[rg], vH = lsumH[rg];
        vL += __shfl_xor(vL, 1); vL += __shfl_xor(vL, 2);
        vL += __shfl_xor(vL, 4); vL += __shfl_xor(vL, 8);
        vH += __shfl_xor(vH, 1); vH += __shfl_xor(vH, 2);
        vH += __shfl_xor(vH, 4); vH += __shfl_xor(vH, 8);
        lsumL[rg] = vL; lsumH[rg] = vH;
    }
    float* OcL = Ob + (size_t)(qtL * 64) * 128;
    float* OcH = Ob + (size_t)(qtH * 64) * 128;
#pragma unroll
    for (int nt = 0; nt < 8; nt++)
#pragma unroll
        for (int rg = 0; rg < 4; rg++) {
            int rl = wv * 16 + quad * 4 + rg;
            OcL[(size_t)rl * 128 + nt * 16 + m16] = oaccL[nt][rg];
            OcH[(size_t)rl * 128 + nt * 16 + m16] = oaccH[nt][rg];
        }
    if (m16 == 0) {
#pragma unroll
        for (int rg = 0; rg < 4; rg++) {
            int rl = wv * 16 + quad * 4 + rg;
            Lb[qtL * 64 + rl] = lsumL[rg];
            Lb[qtH * 64 + rl] = lsumH[rg];
        }
    }
}

// ---------------- cross-config combine: out = sum_c O_c / sum_c L_c ----------------
__global__ __launch_bounds__(256) void k_combine(const char* __restrict__ ws, float* __restrict__ out) {
    int gid = blockIdx.x * 256 + threadIdx.x;
    int rown = gid >> 5;
    int h4 = (gid & 31) * 4;
    int b = rown >> 13, n = rown & 8191;
    const size_t ooff[4] = {O0_OFF, O1_OFF, O2_OFF, O3_OFF};
    const size_t loff[4] = {L0_OFF, L1_OFF, L2_OFF, L3_OFF};
    float denom = 0.f;
    float4 acc = {0.f, 0.f, 0.f, 0.f};
#pragma unroll
    for (int c = 0; c < 4; c++) {
        if ((n & ((1 << c) - 1)) == 0) {
            int s = n >> (10 + c);
            int i = (n & ((1024 << c) - 1)) >> c;
            int rowc = b * (8192 >> c) + (s << 10) + i;
            denom += *((const float*)(ws + loff[c]) + rowc);
            const float4 o = *(const float4*)((const float*)(ws + ooff[c]) + (size_t)rowc * 128 + h4);
            acc.x += o.x; acc.y += o.y; acc.z += o.z; acc.w += o.w;
        }
    }
    float inv = 1.f / denom;
    float4 res = {acc.x * inv, acc.y * inv, acc.z * inv, acc.w * inv};
    *(float4*)(out + (size_t)rown * 128 + h4) = res;
}

extern "C" void kernel_launch(void* const* d_in, const int* in_sizes, int n_in,
                              void* d_out, int out_size, void* d_ws, size_t ws_size,
                              hipStream_t stream) {
    const float* x  = (const float*)d_in[0];
    const float* Wq = (const float*)d_in[1];
    const float* Wk = (const float*)d_in[2];
    const float* Wv = (const float*)d_in[3];
    char* ws = (char*)d_ws;
    unsigned short* Wt  = (unsigned short*)(ws + WT_OFF);
    unsigned short* QKV = (unsigned short*)(ws + QKV_OFF);

    k_wt<<<1536, 256, 0, stream>>>(Wq, Wk, Wv, Wt);
    k_qkv<<<512, 256, 0, stream>>>(x, Wt, QKV);
    k_gather<<<704, 256, 0, stream>>>(QKV, ws);
    k_attn<<<512, 256, 0, stream>>>(QKV, ws);
    k_combine<<<4096, 256, 0, stream>>>(ws, (float*)d_out);
}